// Round 1
// 137.339 us; speedup vs baseline: 1.0261x; 1.0261x over previous
//
#include <hip/hip_runtime.h>

// out[i, :] = weight[b[i], :]  (float32, Y_DIM=32), with out[0, :] = 0.
//
// Structure: one 256-thread block owns a tile of 256 cells (32 KB of output).
//   Phase 1: each thread does ONE coalesced 4B load of b into LDS
//            (b is read exactly once from global, no 8x redundancy).
//   Phase 2: each thread issues 8 independent, fully-coalesced 16B stores
//            (2048 float4s per block). 8x work per block vs. the previous
//            one-store-per-thread version -> 3907 blocks instead of 31250,
//            amortizing per-block kernarg/dispatch latency, and 8-deep
//            store ILP per thread.
// Stores are nontemporal: 128 MB streams through the 32 MB L2 with no reuse.

typedef float f32x4 __attribute__((ext_vector_type(4)));

__global__ __launch_bounds__(256) void batch_effect_gather_kernel(
        const int* __restrict__ b,
        const f32x4* __restrict__ w4,    // weight viewed as [N_BATCHES, 8] float4
        f32x4* __restrict__ out4,        // output viewed as [N, 8] float4
        int n_cells) {
    __shared__ int sb[256];
    const int tid = threadIdx.x;
    const int base_cell = blockIdx.x << 8;

    // Phase 1: stage this block's 256 batch indices in LDS (coalesced).
    int c = base_cell + tid;
    sb[tid] = (c < n_cells) ? b[c] : 0;
    __syncthreads();

    const int base_vec = base_cell << 3;            // first float4 of the tile
    const bool full = (n_cells - base_cell) >= 256; // tail only in last block

    if (full) {
#pragma unroll
        for (int k = 0; k < 8; ++k) {
            int idx = (k << 8) + tid;               // 0..2047 within tile
            int cl  = idx >> 3;                     // cell within tile
            int j   = idx & 7;                      // float4 within row
            f32x4 v = w4[(sb[cl] << 3) + j];        // 8 KB table, L1-resident
            if (base_cell + cl == 0)                // only block 0, cell 0
                v = (f32x4){0.f, 0.f, 0.f, 0.f};
            __builtin_nontemporal_store(v, &out4[base_vec + idx]);
        }
    } else {
#pragma unroll
        for (int k = 0; k < 8; ++k) {
            int idx = (k << 8) + tid;
            int cl  = idx >> 3;
            if (base_cell + cl < n_cells) {
                int j = idx & 7;
                f32x4 v = w4[(sb[cl] << 3) + j];
                __builtin_nontemporal_store(v, &out4[base_vec + idx]);
            }
        }
    }
}

extern "C" void kernel_launch(void* const* d_in, const int* in_sizes, int n_in,
                              void* d_out, int out_size, void* d_ws, size_t ws_size,
                              hipStream_t stream) {
    const int*   b  = (const int*)d_in[0];      // [N, 1] int32
    const f32x4* w4 = (const f32x4*)d_in[1];    // [64, 32] f32 -> [64, 8] float4
    f32x4* out4 = (f32x4*)d_out;                // [N, 32] f32 -> [N, 8] float4

    int n = in_sizes[0];                        // N cells
    int blocks = (n + 255) / 256;               // one block per 256-cell tile
    batch_effect_gather_kernel<<<blocks, 256, 0, stream>>>(b, w4, out4, n);
}

// Round 2
// 133.900 us; speedup vs baseline: 1.0524x; 1.0257x over previous
//
#include <hip/hip_runtime.h>

// out[i, :] = weight[b[i], :]  (float32, Y_DIM=32), with out[0, :] = 0.
//
// Structure: one 256-thread block owns 256 cells (32 KB of output).
//   Phase 0: stage the whole weight table (64 rows x 128 B = 8 KB) in LDS,
//            padded to a row stride of 9 float4s (144 B) so 8 lane-groups
//            reading 8 different rows hit disjoint bank sets
//            (bank base = 4*batch mod 32) instead of an 8-way conflict.
//   Phase 1: stage this block's 256 batch indices in LDS (one coalesced
//            4 B load per thread).
//   Phase 2: per thread, 8 LDS gathers into registers, then 8 plain
//            back-to-back coalesced 16 B stores.
//
// Rationale: the harness fill kernel proves plain pure stores reach
// 6.7 TB/s. This kernel's VMEM queue is now stores-only (gathers moved to
// LDS / lgkmcnt), so store issue is never gated behind global-load latency
// in the in-order vmcnt queue. nt dropped: unverified deviation from the
// demonstrated-good plain-store config.

typedef float f32x4 __attribute__((ext_vector_type(4)));

#define WROWS 64
#define WPAD  9   // LDS row stride in float4s (128 B data + 16 B pad)

__global__ __launch_bounds__(256) void batch_effect_gather_kernel(
        const int* __restrict__ b,
        const f32x4* __restrict__ w4,    // weight as [64, 8] float4
        f32x4* __restrict__ out4,        // output as [N, 8] float4
        int n_cells) {
    __shared__ f32x4 sw[WROWS * WPAD];   // 9216 B
    __shared__ int   sb[256];            // 1024 B
    const int tid = threadIdx.x;
    const int base_cell = blockIdx.x << 8;

    // Phase 0: weight table -> LDS (512 float4s, 2 per thread, coalesced).
#pragma unroll
    for (int t = tid; t < WROWS * 8; t += 256)
        sw[(t >> 3) * WPAD + (t & 7)] = w4[t];

    // Phase 1: this block's batch indices -> LDS (coalesced 4 B/thread).
    int c = base_cell + tid;
    sb[tid] = (c < n_cells) ? b[c] : 0;
    __syncthreads();

    const int j         = tid & 7;   // float4 within the row
    const int lane_cell = tid >> 3;  // cell subgroup within each 32-cell slab
    const int base_vec  = base_cell << 3;

    if (n_cells - base_cell >= 256) {           // full tile (all but last)
        f32x4 v[8];
#pragma unroll
        for (int k = 0; k < 8; ++k) {
            int cl = (k << 5) + lane_cell;      // cell within tile
            v[k] = sw[sb[cl] * WPAD + j];
            if (base_cell + cl == 0)            // out[0,:] = 0 (block 0 only)
                v[k] = (f32x4){0.f, 0.f, 0.f, 0.f};
        }
#pragma unroll
        for (int k = 0; k < 8; ++k)             // pure store burst
            out4[base_vec + (k << 8) + tid] = v[k];
    } else {                                    // tail tile
        for (int k = 0; k < 8; ++k) {
            int cl = (k << 5) + lane_cell;
            if (base_cell + cl < n_cells)
                out4[base_vec + (k << 8) + tid] = sw[sb[cl] * WPAD + j];
        }
    }
}

extern "C" void kernel_launch(void* const* d_in, const int* in_sizes, int n_in,
                              void* d_out, int out_size, void* d_ws, size_t ws_size,
                              hipStream_t stream) {
    const int*   b  = (const int*)d_in[0];      // [N, 1] int32
    const f32x4* w4 = (const f32x4*)d_in[1];    // [64, 32] f32 -> [64, 8] float4
    f32x4* out4 = (f32x4*)d_out;                // [N, 32] f32 -> [N, 8] float4

    int n = in_sizes[0];                        // N cells
    int blocks = (n + 255) / 256;               // one block per 256-cell tile
    batch_effect_gather_kernel<<<blocks, 256, 0, stream>>>(b, w4, out4, n);
}